// Round 1
// baseline (226.772 us; speedup 1.0000x reference)
//
#include <hip/hip_runtime.h>
#include <math.h>

#define FMPX 40
#define NPOS 1600          // 40*40
#define BPC 5
#define NCLS 80
#define NBOX 8000
#define KDIM 512
#define CAP 1024           // per-class candidate capacity (expected ~100/class)

// anchor (w,h) pairs
__constant__ float c_aw[5] = {17.f, 55.f, 92.f, 202.f, 289.f};
__constant__ float c_ah[5] = {25.f, 75.f, 206.f, 21.f, 311.f};

__device__ __forceinline__ float sigf(float x) { return 1.0f / (1.0f + expf(-x)); }

// ---------------------------------------------------------------------------
// K1: the three 1x1-conv GEMMs.
// grid = (100 position-tiles, 5 groups). Groups 0..3: cls outputs oBase=grp*100,
// 100 outs each (uses cls_feat). Group 4: 25 outs = 5 obj + 20 reg (uses reg_feat).
// Block: 256 threads; LDS tile feat[k][pos] 512x16 f32 (32 KB).
// Thread (pos = tid&15, og = tid>>4) accumulates outputs o = og + 16*i, i<7,
// sharing each LDS feature read across its 7 accumulators.
// ---------------------------------------------------------------------------
__global__ __launch_bounds__(256) void k_gemm(
    const float* __restrict__ cls_feat, const float* __restrict__ reg_feat,
    const float* __restrict__ w_obj, const float* __restrict__ b_obj,
    const float* __restrict__ w_cls, const float* __restrict__ b_cls,
    const float* __restrict__ w_reg, const float* __restrict__ b_reg,
    float* __restrict__ clsRaw,   // [1600][400]
    float* __restrict__ roRaw)    // [1600][25]: 0..4 obj, 5..24 reg
{
    __shared__ float tile[KDIM * 16];
    const int tileId = blockIdx.x;     // 0..99
    const int grp    = blockIdx.y;     // 0..4
    const int hw0    = tileId * 16;
    const float* feat = (grp == 4) ? reg_feat : cls_feat;

    for (int idx = threadIdx.x; idx < KDIM * 16; idx += 256) {
        int c = idx >> 4, p = idx & 15;
        tile[idx] = feat[c * NPOS + hw0 + p];
    }
    __syncthreads();

    const int pos = threadIdx.x & 15;
    const int og  = threadIdx.x >> 4;       // 0..15
    const int nOut  = (grp == 4) ? 25 : 100;
    const int oBase = (grp == 4) ? 0  : grp * 100;

    float acc[7];
    const float* wp[7];
    float bias[7];
    bool ok[7];
#pragma unroll
    for (int i = 0; i < 7; i++) {
        int o = og + 16 * i;
        ok[i] = (o < nOut);
        int oc = ok[i] ? o : 0;
        if (grp == 4) {
            if (oc < 5) { wp[i] = w_obj + oc * KDIM;       bias[i] = b_obj[oc]; }
            else        { wp[i] = w_reg + (oc - 5) * KDIM; bias[i] = b_reg[oc - 5]; }
        } else {
            wp[i] = w_cls + (oBase + oc) * KDIM;
            bias[i] = b_cls[oBase + oc];
        }
        acc[i] = 0.0f;
    }

    for (int k = 0; k < KDIM; k += 4) {
        float a0 = tile[(k + 0) * 16 + pos];
        float a1 = tile[(k + 1) * 16 + pos];
        float a2 = tile[(k + 2) * 16 + pos];
        float a3 = tile[(k + 3) * 16 + pos];
#pragma unroll
        for (int i = 0; i < 7; i++) {
            float4 w4 = *(const float4*)(wp[i] + k);
            acc[i] += a0 * w4.x;
            acc[i] += a1 * w4.y;
            acc[i] += a2 * w4.z;
            acc[i] += a3 * w4.w;
        }
    }

    const int hw = hw0 + pos;
#pragma unroll
    for (int i = 0; i < 7; i++) {
        if (ok[i]) {
            int o = og + 16 * i;
            float v = acc[i] + bias[i];
            if (grp == 4) roRaw[hw * 25 + o] = v;
            else          clsRaw[hw * 400 + oBase + o] = v;
        }
    }
}

// ---------------------------------------------------------------------------
// K2: per-box scores, argmax label, decode, outputs, per-class candidate append.
// One 64-lane wave per box (8000 blocks).
// ---------------------------------------------------------------------------
__global__ __launch_bounds__(64) void k_box(
    const float* __restrict__ clsRaw, const float* __restrict__ roRaw,
    float* __restrict__ out,          // d_out: [32000 bboxes][8000 score][8000 labels][8000 keep]
    float4* __restrict__ nmsBox, float* __restrict__ nmsArea,
    float* __restrict__ listScore, int* __restrict__ listIdx, int* __restrict__ counts)
{
    const int n = blockIdx.x;          // box index 0..7999
    const int lane = threadIdx.x;
    const int hw = n / 5, a = n % 5;

    const float sobj = sigf(roRaw[hw * 25 + a]);
    const float* cbase = clsRaw + hw * 400 + a * 80;

    // local best over classes {lane} and {lane+64 (lane<16)}; ties -> lowest class
    float v = sqrtf(sobj * sigf(cbase[lane]));
    int bi = lane;
    if (lane < 16) {
        float s2 = sqrtf(sobj * sigf(cbase[64 + lane]));
        if (s2 > v) { v = s2; bi = 64 + lane; }
    }
#pragma unroll
    for (int off = 32; off >= 1; off >>= 1) {
        float ov = __shfl_xor(v, off);
        int   oi = __shfl_xor(bi, off);
        if (ov > v || (ov == v && oi < bi)) { v = ov; bi = oi; }
    }

    if (lane == 0) {
        const float* rp = roRaw + hw * 25 + 5 + a * 4;
        float r0 = rp[0], r1 = rp[1], r2 = rp[2], r3 = rp[3];
        float gx = (float)(hw % FMPX), gy = (float)(hw / FMPX);
        float cx = (sigf(r0) + gx) * 32.0f;
        float cy = (sigf(r1) + gy) * 32.0f;
        float wv = expf(r2) * c_aw[a];
        float hv = expf(r3) * c_ah[a];
        float x1 = cx - wv * 0.5f, y1 = cy - hv * 0.5f;
        float x2 = cx + wv * 0.5f, y2 = cy + hv * 0.5f;

        out[n * 4 + 0] = x1; out[n * 4 + 1] = y1;
        out[n * 4 + 2] = x2; out[n * 4 + 3] = y2;
        out[32000 + n] = v;
        out[40000 + n] = (float)bi;

        // b2: reinterpret x1y1x2y2 as cxcywh (faithful to the reference nms())
        float nx1 = x1 - x2 * 0.5f, ny1 = y1 - y2 * 0.5f;
        float nx2 = x1 + x2 * 0.5f, ny2 = y1 + y2 * 0.5f;
        nmsBox[n]  = make_float4(nx1, ny1, nx2, ny2);
        nmsArea[n] = (nx2 - nx1) * (ny2 - ny1);

        if (v >= 0.3f) {
            int p = atomicAdd(&counts[bi], 1);
            if (p < CAP) { listScore[bi * CAP + p] = v; listIdx[bi * CAP + p] = n; }
        }
    }
}

// ---------------------------------------------------------------------------
// K3: per-class greedy NMS. One block (256 thr) per class.
// Bitonic sort by (score desc, box-idx asc) == stable argsort(-score) restricted
// to the class, then sequential greedy suppression, then scatter keep bits.
// ---------------------------------------------------------------------------
__global__ __launch_bounds__(256) void k_nms(
    const float* __restrict__ listScore, const int* __restrict__ listIdx,
    const int* __restrict__ counts,
    const float4* __restrict__ nmsBox, const float* __restrict__ nmsArea,
    float* __restrict__ keepOut)
{
    const int c = blockIdx.x;
    int m = counts[c];
    if (m > CAP) m = CAP;

    __shared__ float ss[CAP];
    __shared__ int   si[CAP];
    __shared__ float bx1[CAP], by1[CAP], bx2[CAP], by2[CAP], bar[CAP];
    __shared__ unsigned char supp[CAP];

    for (int i = threadIdx.x; i < CAP; i += 256) {
        if (i < m) { ss[i] = listScore[c * CAP + i]; si[i] = listIdx[c * CAP + i]; }
        else       { ss[i] = -INFINITY;              si[i] = 0x7FFFFFFF; }
    }
    __syncthreads();

    for (int size = 2; size <= CAP; size <<= 1) {
        for (int stride = size >> 1; stride > 0; stride >>= 1) {
            for (int t = threadIdx.x; t < CAP / 2; t += 256) {
                int lo = 2 * stride * (t / stride) + (t % stride);
                int hi = lo + stride;
                bool desc = ((lo & size) == 0);
                float slo = ss[lo], shi = ss[hi];
                int   ilo = si[lo], ihi = si[hi];
                bool loBetter = (slo > shi) || (slo == shi && ilo < ihi);
                bool doSwap = desc ? !loBetter : loBetter;
                if (doSwap) { ss[lo] = shi; ss[hi] = slo; si[lo] = ihi; si[hi] = ilo; }
            }
            __syncthreads();
        }
    }

    for (int i = threadIdx.x; i < m; i += 256) {
        int n = si[i];
        float4 b = nmsBox[n];
        bx1[i] = b.x; by1[i] = b.y; bx2[i] = b.z; by2[i] = b.w;
        bar[i] = nmsArea[n];
        supp[i] = 0;
    }
    __syncthreads();

    for (int k = 0; k < m; k++) {
        if (!supp[k]) {
            float kx1 = bx1[k], ky1 = by1[k], kx2 = bx2[k], ky2 = by2[k], ka = bar[k];
            for (int j = k + 1 + threadIdx.x; j < m; j += 256) {
                float xx1 = fmaxf(kx1, bx1[j]);
                float yy1 = fmaxf(ky1, by1[j]);
                float xx2 = fminf(kx2, bx2[j]);
                float yy2 = fminf(ky2, by2[j]);
                float inter = fmaxf(1e-10f, xx2 - xx1) * fmaxf(1e-10f, yy2 - yy1);
                float iou = inter / ((ka + bar[j] - inter) + 1e-14f);
                if (iou > 0.5f) supp[j] = 1;
            }
        }
        __syncthreads();
    }

    for (int j = threadIdx.x; j < m; j += 256) {
        if (!supp[j]) keepOut[si[j]] = 1.0f;
    }
}

// ---------------------------------------------------------------------------
extern "C" void kernel_launch(void* const* d_in, const int* in_sizes, int n_in,
                              void* d_out, int out_size, void* d_ws, size_t ws_size,
                              hipStream_t stream) {
    const float* cls_feat = (const float*)d_in[0];
    const float* reg_feat = (const float*)d_in[1];
    const float* w_obj    = (const float*)d_in[2];
    const float* b_obj    = (const float*)d_in[3];
    const float* w_cls    = (const float*)d_in[4];
    const float* b_cls    = (const float*)d_in[5];
    const float* w_reg    = (const float*)d_in[6];
    const float* b_reg    = (const float*)d_in[7];

    float* out = (float*)d_out;
    float* ws  = (float*)d_ws;

    // workspace layout (floats)
    float*  clsRaw    = ws;                       // 640000
    float*  roRaw     = ws + 640000;              // 40000
    float4* nmsBox    = (float4*)(ws + 680000);   // 32000 floats (16B-aligned offset)
    float*  nmsArea   = ws + 712000;              // 8000
    float*  listScore = ws + 720000;              // 80*1024
    int*    listIdx   = (int*)(ws + 801920);      // 80*1024
    int*    counts    = (int*)(ws + 883840);      // 80
    // total ~3.54 MB

    hipMemsetAsync(counts, 0, NCLS * sizeof(int), stream);
    hipMemsetAsync(out + 48000, 0, NBOX * sizeof(float), stream);  // keep = 0

    k_gemm<<<dim3(100, 5), 256, 0, stream>>>(cls_feat, reg_feat,
                                             w_obj, b_obj, w_cls, b_cls, w_reg, b_reg,
                                             clsRaw, roRaw);
    k_box<<<NBOX, 64, 0, stream>>>(clsRaw, roRaw, out, nmsBox, nmsArea,
                                   listScore, listIdx, counts);
    k_nms<<<NCLS, 256, 0, stream>>>(listScore, listIdx, counts, nmsBox, nmsArea,
                                    out + 48000);
}

// Round 2
// 208.735 us; speedup vs baseline: 1.0864x; 1.0864x over previous
//
#include <hip/hip_runtime.h>
#include <math.h>

#define FMPX 40
#define NPOS 1600          // 40*40
#define NCLS 80
#define NBOX 8000
#define KDIM 512
#define KC   128           // k-chunk staged in LDS
#define CAP  256           // per-class candidate capacity (expected ~100/class, 15-sigma safe)

// anchor (w,h) pairs
__constant__ float c_aw[5] = {17.f, 55.f, 92.f, 202.f, 289.f};
__constant__ float c_ah[5] = {25.f, 75.f, 206.f, 21.f, 311.f};

__device__ __forceinline__ float sigf(float x) { return 1.0f / (1.0f + expf(-x)); }

// ---------------------------------------------------------------------------
// K1: the three 1x1-conv GEMMs, latency-optimized.
// grid = (25 M-tiles of 64 positions, 27 N-tiles of 16 outputs).
//   nTile 0..24  : cls outputs oBase=nTile*16      (cls_feat -> clsRaw)
//   nTile 25     : ro outputs 0..15  (5 obj + 11 reg)  (reg_feat -> roRaw)
//   nTile 26     : ro outputs 16..24 (+7 pad)          (reg_feat -> roRaw)
// Block 256 thr: lane pos=tid&63, og=tid>>6 owns 4 consecutive outputs.
// Waves are og-uniform -> all W loads are wave-uniform broadcasts (no L1 thrash).
// A staged in LDS in KC=128 chunks (32 KB). Per-acc FMA order is strictly
// sequential ascending k — bitwise-identical to the R1 kernel (argmax ties!).
// ---------------------------------------------------------------------------
__global__ __launch_bounds__(256) void k_gemm(
    const float* __restrict__ cls_feat, const float* __restrict__ reg_feat,
    const float* __restrict__ w_obj, const float* __restrict__ b_obj,
    const float* __restrict__ w_cls, const float* __restrict__ b_cls,
    const float* __restrict__ w_reg, const float* __restrict__ b_reg,
    float* __restrict__ clsRaw,   // [1600][400]
    float* __restrict__ roRaw)    // [1600][25]: 0..4 obj, 5..24 reg
{
    __shared__ float As[KC * 64];
    const int mTile = blockIdx.x;          // 0..24
    const int nTile = blockIdx.y;          // 0..26
    const int hw0   = mTile * 64;
    const bool isCls = (nTile < 25);
    const float* feat = isCls ? cls_feat : reg_feat;

    const int pos = threadIdx.x & 63;
    const int og  = threadIdx.x >> 6;      // 0..3

    const float* wrow[4];
    float bias[4];
    bool ok[4];
    int oBase = isCls ? nTile * 16 : 0;    // cls: global out base
    int nLoc  = isCls ? 0 : (nTile == 25 ? 0 : 16);
#pragma unroll
    for (int j = 0; j < 4; j++) {
        if (isCls) {
            int o = oBase + 4 * og + j;
            wrow[j] = w_cls + o * KDIM; bias[j] = b_cls[o]; ok[j] = true;
        } else {
            int o = nLoc + 4 * og + j;   // 0..31 over the two ro tiles
            if (o < 5)       { wrow[j] = w_obj + o * KDIM;       bias[j] = b_obj[o];     ok[j] = true; }
            else if (o < 25) { wrow[j] = w_reg + (o - 5) * KDIM; bias[j] = b_reg[o - 5]; ok[j] = true; }
            else             { wrow[j] = w_obj;                  bias[j] = 0.0f;         ok[j] = false; }
        }
    }

    float acc[4] = {0.f, 0.f, 0.f, 0.f};

    for (int kc = 0; kc < KDIM; kc += KC) {
        // stage A chunk: [KC][64], 2048 float4
        for (int i = threadIdx.x; i < KC * 16; i += 256) {
            int r = i >> 4, c4 = (i & 15) << 2;
            *(float4*)&As[r * 64 + c4] = *(const float4*)&feat[(kc + r) * NPOS + hw0 + c4];
        }
        __syncthreads();

        for (int kk = 0; kk < KC; kk += 8) {
            float a[8];
#pragma unroll
            for (int t = 0; t < 8; t++) a[t] = As[(kk + t) * 64 + pos];
#pragma unroll
            for (int j = 0; j < 4; j++) {
                const float* wp = wrow[j] + kc + kk;
                float4 wA = *(const float4*)wp;
                float4 wB = *(const float4*)(wp + 4);
                acc[j] += a[0] * wA.x; acc[j] += a[1] * wA.y;
                acc[j] += a[2] * wA.z; acc[j] += a[3] * wA.w;
                acc[j] += a[4] * wB.x; acc[j] += a[5] * wB.y;
                acc[j] += a[6] * wB.z; acc[j] += a[7] * wB.w;
            }
        }
        __syncthreads();
    }

    const int hw = hw0 + pos;
    if (isCls) {
        float4 r = make_float4(acc[0] + bias[0], acc[1] + bias[1],
                               acc[2] + bias[2], acc[3] + bias[3]);
        *(float4*)&clsRaw[hw * 400 + oBase + 4 * og] = r;
    } else {
#pragma unroll
        for (int j = 0; j < 4; j++) {
            int o = nLoc + 4 * og + j;
            if (ok[j]) roRaw[hw * 25 + o] = acc[j] + bias[j];
        }
    }
}

// ---------------------------------------------------------------------------
// K2: per-box scores, argmax label, decode, outputs, per-class candidate append.
// One 64-lane wave per box (8000 blocks). Also zeroes the keep region.
// ---------------------------------------------------------------------------
__global__ __launch_bounds__(64) void k_box(
    const float* __restrict__ clsRaw, const float* __restrict__ roRaw,
    float* __restrict__ out,          // d_out: [32000 bboxes][8000 score][8000 labels][8000 keep]
    float4* __restrict__ nmsBox, float* __restrict__ nmsArea,
    float* __restrict__ listScore, int* __restrict__ listIdx, int* __restrict__ counts)
{
    const int n = blockIdx.x;          // box index 0..7999
    const int lane = threadIdx.x;
    const int hw = n / 5, a = n % 5;

    const float sobj = sigf(roRaw[hw * 25 + a]);
    const float* cbase = clsRaw + hw * 400 + a * 80;

    // local best over classes {lane} and {lane+64 (lane<16)}; ties -> lowest class
    float v = sqrtf(sobj * sigf(cbase[lane]));
    int bi = lane;
    if (lane < 16) {
        float s2 = sqrtf(sobj * sigf(cbase[64 + lane]));
        if (s2 > v) { v = s2; bi = 64 + lane; }
    }
#pragma unroll
    for (int off = 32; off >= 1; off >>= 1) {
        float ov = __shfl_xor(v, off);
        int   oi = __shfl_xor(bi, off);
        if (ov > v || (ov == v && oi < bi)) { v = ov; bi = oi; }
    }

    if (lane == 0) {
        const float* rp = roRaw + hw * 25 + 5 + a * 4;
        float r0 = rp[0], r1 = rp[1], r2 = rp[2], r3 = rp[3];
        float gx = (float)(hw % FMPX), gy = (float)(hw / FMPX);
        float cx = (sigf(r0) + gx) * 32.0f;
        float cy = (sigf(r1) + gy) * 32.0f;
        float wv = expf(r2) * c_aw[a];
        float hv = expf(r3) * c_ah[a];
        float x1 = cx - wv * 0.5f, y1 = cy - hv * 0.5f;
        float x2 = cx + wv * 0.5f, y2 = cy + hv * 0.5f;

        out[n * 4 + 0] = x1; out[n * 4 + 1] = y1;
        out[n * 4 + 2] = x2; out[n * 4 + 3] = y2;
        out[32000 + n] = v;
        out[40000 + n] = (float)bi;
        out[48000 + n] = 0.0f;            // keep init (k_nms sets 1s later)

        // b2: reinterpret x1y1x2y2 as cxcywh (faithful to the reference nms())
        float nx1 = x1 - x2 * 0.5f, ny1 = y1 - y2 * 0.5f;
        float nx2 = x1 + x2 * 0.5f, ny2 = y1 + y2 * 0.5f;
        nmsBox[n]  = make_float4(nx1, ny1, nx2, ny2);
        nmsArea[n] = (nx2 - nx1) * (ny2 - ny1);

        if (v >= 0.3f) {
            int p = atomicAdd(&counts[bi], 1);
            if (p < CAP) { listScore[bi * CAP + p] = v; listIdx[bi * CAP + p] = n; }
        }
    }
}

// ---------------------------------------------------------------------------
// K3: per-class greedy NMS. ONE WAVE (64 thr) per class -> barriers are
// intra-wave (near-free). Bitonic sort of CAP=256 by (score desc, idx asc)
// == stable argsort(-score) restricted to the class, then greedy suppression.
// ---------------------------------------------------------------------------
__global__ __launch_bounds__(64) void k_nms(
    const float* __restrict__ listScore, const int* __restrict__ listIdx,
    const int* __restrict__ counts,
    const float4* __restrict__ nmsBox, const float* __restrict__ nmsArea,
    float* __restrict__ keepOut)
{
    const int c = blockIdx.x;
    int m = counts[c];
    if (m > CAP) m = CAP;

    __shared__ float ss[CAP];
    __shared__ int   si[CAP];
    __shared__ float bx1[CAP], by1[CAP], bx2[CAP], by2[CAP], bar[CAP];
    __shared__ int   supp[CAP];

    for (int i = threadIdx.x; i < CAP; i += 64) {
        if (i < m) { ss[i] = listScore[c * CAP + i]; si[i] = listIdx[c * CAP + i]; }
        else       { ss[i] = -INFINITY;              si[i] = 0x7FFFFFFF; }
    }
    __syncthreads();

    for (int size = 2; size <= CAP; size <<= 1) {
        for (int stride = size >> 1; stride > 0; stride >>= 1) {
            for (int t = threadIdx.x; t < CAP / 2; t += 64) {
                int lo = 2 * stride * (t / stride) + (t % stride);
                int hi = lo + stride;
                bool desc = ((lo & size) == 0);
                float slo = ss[lo], shi = ss[hi];
                int   ilo = si[lo], ihi = si[hi];
                bool loBetter = (slo > shi) || (slo == shi && ilo < ihi);
                bool doSwap = desc ? !loBetter : loBetter;
                if (doSwap) { ss[lo] = shi; ss[hi] = slo; si[lo] = ihi; si[hi] = ilo; }
            }
            __syncthreads();
        }
    }

    for (int i = threadIdx.x; i < m; i += 64) {
        int n = si[i];
        float4 b = nmsBox[n];
        bx1[i] = b.x; by1[i] = b.y; bx2[i] = b.z; by2[i] = b.w;
        bar[i] = nmsArea[n];
        supp[i] = 0;
    }
    __syncthreads();

    for (int k = 0; k < m; k++) {
        if (!supp[k]) {
            float kx1 = bx1[k], ky1 = by1[k], kx2 = bx2[k], ky2 = by2[k], ka = bar[k];
            for (int j = k + 1 + threadIdx.x; j < m; j += 64) {
                float xx1 = fmaxf(kx1, bx1[j]);
                float yy1 = fmaxf(ky1, by1[j]);
                float xx2 = fminf(kx2, bx2[j]);
                float yy2 = fminf(ky2, by2[j]);
                float inter = fmaxf(1e-10f, xx2 - xx1) * fmaxf(1e-10f, yy2 - yy1);
                float iou = inter / ((ka + bar[j] - inter) + 1e-14f);
                if (iou > 0.5f) supp[j] = 1;
            }
        }
        __syncthreads();
    }

    for (int j = threadIdx.x; j < m; j += 64) {
        if (!supp[j]) keepOut[si[j]] = 1.0f;
    }
}

// ---------------------------------------------------------------------------
extern "C" void kernel_launch(void* const* d_in, const int* in_sizes, int n_in,
                              void* d_out, int out_size, void* d_ws, size_t ws_size,
                              hipStream_t stream) {
    const float* cls_feat = (const float*)d_in[0];
    const float* reg_feat = (const float*)d_in[1];
    const float* w_obj    = (const float*)d_in[2];
    const float* b_obj    = (const float*)d_in[3];
    const float* w_cls    = (const float*)d_in[4];
    const float* b_cls    = (const float*)d_in[5];
    const float* w_reg    = (const float*)d_in[6];
    const float* b_reg    = (const float*)d_in[7];

    float* out = (float*)d_out;
    float* ws  = (float*)d_ws;

    // workspace layout (floats)
    float*  clsRaw    = ws;                       // 640000
    float*  roRaw     = ws + 640000;              // 40000
    float4* nmsBox    = (float4*)(ws + 680000);   // 32000 floats (16B-aligned offset)
    float*  nmsArea   = ws + 712000;              // 8000
    float*  listScore = ws + 720000;              // 80*256 = 20480
    int*    listIdx   = (int*)(ws + 740480);      // 80*256
    int*    counts    = (int*)(ws + 760960);      // 80
    // total ~3.05 MB

    hipMemsetAsync(counts, 0, NCLS * sizeof(int), stream);

    k_gemm<<<dim3(25, 27), 256, 0, stream>>>(cls_feat, reg_feat,
                                             w_obj, b_obj, w_cls, b_cls, w_reg, b_reg,
                                             clsRaw, roRaw);
    k_box<<<NBOX, 64, 0, stream>>>(clsRaw, roRaw, out, nmsBox, nmsArea,
                                   listScore, listIdx, counts);
    k_nms<<<NCLS, 64, 0, stream>>>(listScore, listIdx, counts, nmsBox, nmsArea,
                                   out + 48000);
}

// Round 3
// 184.783 us; speedup vs baseline: 1.2272x; 1.1296x over previous
//
#include <hip/hip_runtime.h>
#include <math.h>

#define FMPX 40
#define NPOS 1600          // 40*40
#define NCLS 80
#define NBOX 8000
#define KDIM 512
#define KC   64            // k-chunk staged in LDS
#define CAP  256           // per-class candidate capacity (expected ~100/class)

// anchor (w,h) pairs
__constant__ float c_aw[5] = {17.f, 55.f, 92.f, 202.f, 289.f};
__constant__ float c_ah[5] = {25.f, 75.f, 206.f, 21.f, 311.f};

__device__ __forceinline__ float sigf(float x) { return 1.0f / (1.0f + expf(-x)); }

// ---------------------------------------------------------------------------
// K1: the three 1x1-conv GEMMs. ALL inner-loop operands LDS-resident:
// R2's lesson (FETCH 19.5MB, ~985cyc/step): per-step VMEM weight loads were
// L2-thrashed by streaming A traffic -> dependent HBM misses. Fix: stage the
// block's 16 weight rows (32 KB) in LDS once; A in KC=64 chunks (16 KB).
// grid = (25 M-tiles of 64 pos, 27 N-tiles of 16 outs):
//   nTile 0..24: cls outs oBase=nTile*16 (cls_feat); 25/26: the 25 ro outs.
// Block 256: pos=tid&63, og=tid>>6 owns rows og*4..og*4+3 of the W tile.
// w reads are wave-uniform LDS addresses -> broadcast, conflict-free; a reads
// stride-1 across lanes -> conflict-free. Per-acc FMA order strictly
// sequential ascending k — bitwise-identical to R1/R2 (argmax tie safety).
// ---------------------------------------------------------------------------
__global__ __launch_bounds__(256) void k_gemm(
    const float* __restrict__ cls_feat, const float* __restrict__ reg_feat,
    const float* __restrict__ w_obj, const float* __restrict__ b_obj,
    const float* __restrict__ w_cls, const float* __restrict__ b_cls,
    const float* __restrict__ w_reg, const float* __restrict__ b_reg,
    float* __restrict__ clsRaw,   // [1600][400]
    float* __restrict__ roRaw)    // [1600][25]: 0..4 obj, 5..24 reg
{
    __shared__ float Ws[16 * KDIM];   // 32 KB
    __shared__ float As[KC * 64];     // 16 KB
    const int mTile = blockIdx.x;          // 0..24
    const int nTile = blockIdx.y;          // 0..26
    const int hw0   = mTile * 64;
    const bool isCls = (nTile < 25);
    const float* feat = isCls ? cls_feat : reg_feat;

    const int pos = threadIdx.x & 63;
    const int og  = threadIdx.x >> 6;      // 0..3 (wave-uniform)

    // ---- stage W tile [16][512] (coalesced float4; 8 iters/thread) ----
    for (int i = threadIdx.x * 4; i < 16 * KDIM; i += 256 * 4) {
        int r = i >> 9, k = i & 511;
        const float* src;
        bool valid = true;
        if (isCls) {
            src = w_cls + (nTile * 16 + r) * KDIM + k;
        } else {
            int o = (nTile - 25) * 16 + r;
            if (o < 5)       src = w_obj + o * KDIM + k;
            else if (o < 25) src = w_reg + (o - 5) * KDIM + k;
            else           { src = w_obj; valid = false; }
        }
        float4 v = valid ? *(const float4*)src : make_float4(0.f, 0.f, 0.f, 0.f);
        *(float4*)&Ws[i] = v;
    }

    // ---- per-thread output metadata (wave-uniform) ----
    float bias[4];
    bool ok[4];
#pragma unroll
    for (int j = 0; j < 4; j++) {
        int r = og * 4 + j;                // row within the 16-wide tile
        if (isCls) {
            bias[j] = b_cls[nTile * 16 + r]; ok[j] = true;
        } else {
            int o = (nTile - 25) * 16 + r;
            if (o < 5)       { bias[j] = b_obj[o];     ok[j] = true; }
            else if (o < 25) { bias[j] = b_reg[o - 5]; ok[j] = true; }
            else             { bias[j] = 0.0f;         ok[j] = false; }
        }
    }

    float acc[4] = {0.f, 0.f, 0.f, 0.f};
    const float* wsBase = &Ws[(og * 4) * KDIM];

    for (int kc = 0; kc < KDIM; kc += KC) {
        // stage A chunk [KC][64] (1024 float4; 4 iters/thread)
        for (int i = threadIdx.x * 4; i < KC * 64; i += 256 * 4) {
            int r = i >> 6, c = i & 63;
            *(float4*)&As[i] = *(const float4*)&feat[(kc + r) * NPOS + hw0 + c];
        }
        __syncthreads();

        for (int kk = 0; kk < KC; kk += 8) {
            float a[8];
#pragma unroll
            for (int t = 0; t < 8; t++) a[t] = As[(kk + t) * 64 + pos];
#pragma unroll
            for (int j = 0; j < 4; j++) {
                const float* wp = wsBase + j * KDIM + kc + kk;   // LDS, wave-uniform addr
                float4 wA = *(const float4*)wp;
                float4 wB = *(const float4*)(wp + 4);
                acc[j] += a[0] * wA.x; acc[j] += a[1] * wA.y;
                acc[j] += a[2] * wA.z; acc[j] += a[3] * wA.w;
                acc[j] += a[4] * wB.x; acc[j] += a[5] * wB.y;
                acc[j] += a[6] * wB.z; acc[j] += a[7] * wB.w;
            }
        }
        __syncthreads();
    }

    const int hw = hw0 + pos;
    if (isCls) {
        float4 rv = make_float4(acc[0] + bias[0], acc[1] + bias[1],
                                acc[2] + bias[2], acc[3] + bias[3]);
        *(float4*)&clsRaw[hw * 400 + nTile * 16 + og * 4] = rv;
    } else {
#pragma unroll
        for (int j = 0; j < 4; j++) {
            int o = (nTile - 25) * 16 + og * 4 + j;
            if (ok[j]) roRaw[hw * 25 + o] = acc[j] + bias[j];
        }
    }
}

// ---------------------------------------------------------------------------
// K2: per-box scores, argmax label, decode, outputs, per-class candidate append.
// 2000 blocks x 256 thr; each of the 4 waves handles one box independently.
// ---------------------------------------------------------------------------
__global__ __launch_bounds__(256) void k_box(
    const float* __restrict__ clsRaw, const float* __restrict__ roRaw,
    float* __restrict__ out,          // d_out: [32000 bboxes][8000 score][8000 labels][8000 keep]
    float4* __restrict__ nmsBox, float* __restrict__ nmsArea,
    float* __restrict__ listScore, int* __restrict__ listIdx, int* __restrict__ counts)
{
    const int n = blockIdx.x * 4 + (threadIdx.x >> 6);   // box index 0..7999
    const int lane = threadIdx.x & 63;
    const int hw = n / 5, a = n % 5;

    const float sobj = sigf(roRaw[hw * 25 + a]);
    const float* cbase = clsRaw + hw * 400 + a * 80;

    // local best over classes {lane} and {lane+64 (lane<16)}; ties -> lowest class
    float v = sqrtf(sobj * sigf(cbase[lane]));
    int bi = lane;
    if (lane < 16) {
        float s2 = sqrtf(sobj * sigf(cbase[64 + lane]));
        if (s2 > v) { v = s2; bi = 64 + lane; }
    }
#pragma unroll
    for (int off = 32; off >= 1; off >>= 1) {
        float ov = __shfl_xor(v, off);
        int   oi = __shfl_xor(bi, off);
        if (ov > v || (ov == v && oi < bi)) { v = ov; bi = oi; }
    }

    if (lane == 0) {
        const float* rp = roRaw + hw * 25 + 5 + a * 4;
        float r0 = rp[0], r1 = rp[1], r2 = rp[2], r3 = rp[3];
        float gx = (float)(hw % FMPX), gy = (float)(hw / FMPX);
        float cx = (sigf(r0) + gx) * 32.0f;
        float cy = (sigf(r1) + gy) * 32.0f;
        float wv = expf(r2) * c_aw[a];
        float hv = expf(r3) * c_ah[a];
        float x1 = cx - wv * 0.5f, y1 = cy - hv * 0.5f;
        float x2 = cx + wv * 0.5f, y2 = cy + hv * 0.5f;

        out[n * 4 + 0] = x1; out[n * 4 + 1] = y1;
        out[n * 4 + 2] = x2; out[n * 4 + 3] = y2;
        out[32000 + n] = v;
        out[40000 + n] = (float)bi;
        out[48000 + n] = 0.0f;            // keep init (k_nms sets 1s later)

        // b2: reinterpret x1y1x2y2 as cxcywh (faithful to the reference nms())
        float nx1 = x1 - x2 * 0.5f, ny1 = y1 - y2 * 0.5f;
        float nx2 = x1 + x2 * 0.5f, ny2 = y1 + y2 * 0.5f;
        nmsBox[n]  = make_float4(nx1, ny1, nx2, ny2);
        nmsArea[n] = (nx2 - nx1) * (ny2 - ny1);

        if (v >= 0.3f) {
            int p = atomicAdd(&counts[bi], 1);
            if (p < CAP) { listScore[bi * CAP + p] = v; listIdx[bi * CAP + p] = n; }
        }
    }
}

// ---------------------------------------------------------------------------
// K3: per-class greedy NMS. ONE WAVE (64 thr) per class. Bitonic sort over
// P = next-pow2(m) <= CAP by (score desc, idx asc) == stable argsort(-score)
// restricted to the class, then greedy suppression, then scatter keep bits.
// ---------------------------------------------------------------------------
__global__ __launch_bounds__(64) void k_nms(
    const float* __restrict__ listScore, const int* __restrict__ listIdx,
    const int* __restrict__ counts,
    const float4* __restrict__ nmsBox, const float* __restrict__ nmsArea,
    float* __restrict__ keepOut)
{
    const int c = blockIdx.x;
    int m = counts[c];
    if (m > CAP) m = CAP;

    // P = next pow2 >= m (min 2); elements >= P are never touched/read.
    int P = 2;
    while (P < m) P <<= 1;

    __shared__ float ss[CAP];
    __shared__ int   si[CAP];
    __shared__ float bx1[CAP], by1[CAP], bx2[CAP], by2[CAP], bar[CAP];
    __shared__ int   supp[CAP];

    for (int i = threadIdx.x; i < P; i += 64) {
        if (i < m) { ss[i] = listScore[c * CAP + i]; si[i] = listIdx[c * CAP + i]; }
        else       { ss[i] = -INFINITY;              si[i] = 0x7FFFFFFF; }
    }
    __syncthreads();

    for (int size = 2; size <= P; size <<= 1) {
        for (int stride = size >> 1; stride > 0; stride >>= 1) {
            for (int t = threadIdx.x; t < P / 2; t += 64) {
                int lo = 2 * stride * (t / stride) + (t % stride);
                int hi = lo + stride;
                bool desc = ((lo & size) == 0);
                float slo = ss[lo], shi = ss[hi];
                int   ilo = si[lo], ihi = si[hi];
                bool loBetter = (slo > shi) || (slo == shi && ilo < ihi);
                bool doSwap = desc ? !loBetter : loBetter;
                if (doSwap) { ss[lo] = shi; ss[hi] = slo; si[lo] = ihi; si[hi] = ilo; }
            }
            __syncthreads();
        }
    }

    for (int i = threadIdx.x; i < m; i += 64) {
        int n = si[i];
        float4 b = nmsBox[n];
        bx1[i] = b.x; by1[i] = b.y; bx2[i] = b.z; by2[i] = b.w;
        bar[i] = nmsArea[n];
        supp[i] = 0;
    }
    __syncthreads();

    for (int k = 0; k < m; k++) {
        if (!supp[k]) {
            float kx1 = bx1[k], ky1 = by1[k], kx2 = bx2[k], ky2 = by2[k], ka = bar[k];
            for (int j = k + 1 + threadIdx.x; j < m; j += 64) {
                float xx1 = fmaxf(kx1, bx1[j]);
                float yy1 = fmaxf(ky1, by1[j]);
                float xx2 = fminf(kx2, bx2[j]);
                float yy2 = fminf(ky2, by2[j]);
                float inter = fmaxf(1e-10f, xx2 - xx1) * fmaxf(1e-10f, yy2 - yy1);
                float iou = inter / ((ka + bar[j] - inter) + 1e-14f);
                if (iou > 0.5f) supp[j] = 1;
            }
        }
        __syncthreads();
    }

    for (int j = threadIdx.x; j < m; j += 64) {
        if (!supp[j]) keepOut[si[j]] = 1.0f;
    }
}

// ---------------------------------------------------------------------------
extern "C" void kernel_launch(void* const* d_in, const int* in_sizes, int n_in,
                              void* d_out, int out_size, void* d_ws, size_t ws_size,
                              hipStream_t stream) {
    const float* cls_feat = (const float*)d_in[0];
    const float* reg_feat = (const float*)d_in[1];
    const float* w_obj    = (const float*)d_in[2];
    const float* b_obj    = (const float*)d_in[3];
    const float* w_cls    = (const float*)d_in[4];
    const float* b_cls    = (const float*)d_in[5];
    const float* w_reg    = (const float*)d_in[6];
    const float* b_reg    = (const float*)d_in[7];

    float* out = (float*)d_out;
    float* ws  = (float*)d_ws;

    // workspace layout (floats)
    float*  clsRaw    = ws;                       // 640000
    float*  roRaw     = ws + 640000;              // 40000
    float4* nmsBox    = (float4*)(ws + 680000);   // 32000 floats (16B-aligned offset)
    float*  nmsArea   = ws + 712000;              // 8000
    float*  listScore = ws + 720000;              // 80*256 = 20480
    int*    listIdx   = (int*)(ws + 740480);      // 80*256
    int*    counts    = (int*)(ws + 760960);      // 80
    // total ~3.05 MB

    hipMemsetAsync(counts, 0, NCLS * sizeof(int), stream);

    k_gemm<<<dim3(25, 27), 256, 0, stream>>>(cls_feat, reg_feat,
                                             w_obj, b_obj, w_cls, b_cls, w_reg, b_reg,
                                             clsRaw, roRaw);
    k_box<<<NBOX / 4, 256, 0, stream>>>(clsRaw, roRaw, out, nmsBox, nmsArea,
                                        listScore, listIdx, counts);
    k_nms<<<NCLS, 64, 0, stream>>>(listScore, listIdx, counts, nmsBox, nmsArea,
                                   out + 48000);
}